// Round 1
// baseline (128.549 us; speedup 1.0000x reference)
//
#include <hip/hip_runtime.h>

// EdgeFeatureEncoding: proj = edge_attr @ W + b  (E x 8), scatter-add into
// dense (N, N, 8) bias at (i, j) with validity mask.
//
// Phase 1: hipMemsetAsync zeroes the 512 MiB output (fill roofline).
// Phase 2: scatter kernel — 16 lanes per edge, coalesced float4 row loads,
//          W rows held in registers, shfl_xor group reduction, 8 fp32 atomics
//          per edge (lanes 0..7 of each 16-lane group).

__global__ __launch_bounds__(256) void efe_scatter_kernel(
    const int* __restrict__ ei,      // (2, E) row-major: ei[e]=i, ei[E+e]=j
    const float* __restrict__ attr,  // (E, 128)
    const int* __restrict__ nn,      // num_nodes (1 element, device)
    const float* __restrict__ Wm,    // (128, 8)
    const float* __restrict__ bv,    // (8,)
    float* __restrict__ out,         // (N, N, 8), pre-zeroed
    int E)
{
    const int N = nn[0];
    const int tid    = blockIdx.x * blockDim.x + threadIdx.x;
    const int wave   = tid >> 6;                       // global wave id
    const int lane   = threadIdx.x & 63;
    const int lg     = lane & 15;                      // lane within 16-lane group
    const int sub    = lane >> 4;                      // edge slot within wave (0..3)
    const int nwaves = (gridDim.x * blockDim.x) >> 6;

    // Preload this lane's slice of W into registers: rows k = half*64 + lg*4 + c.
    // 2*4*8 = 64 floats; reused across all grid-stride iterations (L1-served once).
    float w[2][4][8];
#pragma unroll
    for (int half = 0; half < 2; ++half)
#pragma unroll
        for (int c = 0; c < 4; ++c) {
            const int k = half * 64 + lg * 4 + c;
#pragma unroll
            for (int h = 0; h < 8; ++h) w[half][c][h] = Wm[k * 8 + h];
        }
    float bh[8];
#pragma unroll
    for (int h = 0; h < 8; ++h) bh[h] = bv[h];

    const int nquads = (E + 3) >> 2;  // 4 edges per wave-iteration
    for (int q = wave; q < nquads; q += nwaves) {
        const int e = q * 4 + sub;
        float acc[8];
#pragma unroll
        for (int h = 0; h < 8; ++h) acc[h] = 0.f;

        const bool live = (e < E);
        if (live) {
            // 16 lanes x float4 = the full 128-float row, coalesced.
            const float4* row = (const float4*)(attr + (size_t)e * 128);
#pragma unroll
            for (int half = 0; half < 2; ++half) {
                const float4 v = row[half * 16 + lg];
#pragma unroll
                for (int h = 0; h < 8; ++h)
                    acc[h] += v.x * w[half][0][h] + v.y * w[half][1][h]
                            + v.z * w[half][2][h] + v.w * w[half][3][h];
            }
        }
        // Tree-reduce each head across the 16-lane group (xor masks 1,2,4,8
        // stay within the group on wave64). Dead lanes contribute 0.
#pragma unroll
        for (int d = 1; d < 16; d <<= 1)
#pragma unroll
            for (int h = 0; h < 8; ++h)
                acc[h] += __shfl_xor(acc[h], d, 64);

        if (live && lg < 8) {
            const int i = ei[e];
            const int j = ei[E + e];
            if (i >= 0 && i < N && j >= 0 && j < N) {
                // Lane lg handles head lg: select acc[lg]+bh[lg] via an
                // unrolled cndmask chain (no runtime register indexing).
                float v = acc[0] + bh[0];
#pragma unroll
                for (int h = 1; h < 8; ++h) {
                    const float cand = acc[h] + bh[h];
                    v = (lg == h) ? cand : v;
                }
                atomicAdd(out + (((size_t)i * N + j) << 3) + lg, v);
            }
        }
    }
}

extern "C" void kernel_launch(void* const* d_in, const int* in_sizes, int n_in,
                              void* d_out, int out_size, void* d_ws, size_t ws_size,
                              hipStream_t stream) {
    const int*   ei   = (const int*)d_in[0];    // edge_index (2, E) int32
    const float* attr = (const float*)d_in[1];  // edge_attr (E, 128) f32
    const int*   nn   = (const int*)d_in[2];    // num_nodes scalar
    const float* Wm   = (const float*)d_in[3];  // W (128, 8) f32
    const float* bv   = (const float*)d_in[4];  // b (8,) f32
    float*       out  = (float*)d_out;          // (N, N, 8) f32

    const int E = in_sizes[0] / 2;

    // Output must be zeroed every call (harness poisons once, never re-poisons).
    hipMemsetAsync(d_out, 0, (size_t)out_size * sizeof(float), stream);

    // 2048 blocks x 256 threads = 8192 waves; grid-stride over E/4 = 32768
    // edge-quads (4 iterations/wave) so the register-held W amortizes.
    efe_scatter_kernel<<<2048, 256, 0, stream>>>(ei, attr, nn, Wm, bv, out, E);
}